// Round 1
// baseline (607.501 us; speedup 1.0000x reference)
//
#include <hip/hip_runtime.h>

#define BS   64
#define Q    300
#define K    91
#define T    4096
#define TPER 64
#define M    300   // Hungarian cols (queries)
#define NROW 64    // Hungarian rows (targets per batch)

// ---------------------------------------------------------------------------
// Kernel 1: cost matrix C[bs, q, t] = 5*L1(box) - prob[label] - 2*giou
// grid: BS*Q/4 blocks (4 (b,q) rows per block), 256 threads
// ---------------------------------------------------------------------------
__global__ __launch_bounds__(256) void cost_kernel(
    const float* __restrict__ probs,    // [BS,Q,K]
    const float* __restrict__ pboxes,   // [BS,Q,4] cxcywh
    const float* __restrict__ tboxes,   // [T,4]   cxcywh
    const int*   __restrict__ tlabels,  // [T]
    float* __restrict__ C)              // [BS,Q,T]
{
    __shared__ float sprobs[4][K];
    const int tid = threadIdx.x;
    const int bq0 = blockIdx.x * 4;

    // stage 4 prob rows (contiguous 4*K floats)
    for (int idx = tid; idx < 4 * K; idx += 256)
        sprobs[idx / K][idx % K] = probs[(size_t)bq0 * K + idx];

    // per-row pred box + derived xyxy/area (as reference computes them)
    float pcx[4], pcy[4], pw[4], ph[4];
    float px0[4], py0[4], px1[4], py1[4], pare[4];
#pragma unroll
    for (int r = 0; r < 4; ++r) {
        float4 pb = ((const float4*)pboxes)[bq0 + r];
        pcx[r] = pb.x; pcy[r] = pb.y; pw[r] = pb.z; ph[r] = pb.w;
        px0[r] = pb.x - pb.z * 0.5f;  py0[r] = pb.y - pb.w * 0.5f;
        px1[r] = pb.x + pb.z * 0.5f;  py1[r] = pb.y + pb.w * 0.5f;
        pare[r] = (px1[r] - px0[r]) * (py1[r] - py0[r]);
    }
    __syncthreads();

    // 4096 targets in 4 chunks; each thread: 4 consecutive targets per chunk
#pragma unroll
    for (int c = 0; c < 4; ++c) {
        const int t0 = (c << 10) + (tid << 2);
        const int4 lb4 = *(const int4*)(tlabels + t0);
        const int lab[4] = { lb4.x, lb4.y, lb4.z, lb4.w };
        float out[4][4];
#pragma unroll
        for (int k = 0; k < 4; ++k) {
            float4 tb = ((const float4*)tboxes)[t0 + k];
            const float tx0 = tb.x - tb.z * 0.5f, ty0 = tb.y - tb.w * 0.5f;
            const float tx1 = tb.x + tb.z * 0.5f, ty1 = tb.y + tb.w * 0.5f;
            const float tarea = (tx1 - tx0) * (ty1 - ty0);
#pragma unroll
            for (int r = 0; r < 4; ++r) {
                // L1 in cxcywh
                float bb = fabsf(pcx[r] - tb.x) + fabsf(pcy[r] - tb.y)
                         + fabsf(pw[r]  - tb.z) + fabsf(ph[r]  - tb.w);
                // IoU
                float ltx = fmaxf(px0[r], tx0), lty = fmaxf(py0[r], ty0);
                float rbx = fminf(px1[r], tx1), rby = fminf(py1[r], ty1);
                float iw = fmaxf(rbx - ltx, 0.f), ih = fmaxf(rby - lty, 0.f);
                float inter = iw * ih;
                float uni   = pare[r] + tarea - inter;
                float iou   = inter / uni;
                // enclosing box
                float cx0 = fminf(px0[r], tx0), cy0 = fminf(py0[r], ty0);
                float cx1 = fmaxf(px1[r], tx1), cy1 = fmaxf(py1[r], ty1);
                float cw  = fmaxf(cx1 - cx0, 0.f), chh = fmaxf(cy1 - cy0, 0.f);
                float carea = cw * chh;
                float giou  = iou - (carea - uni) / carea;
                float prob  = sprobs[r][lab[k]];
                out[r][k] = 5.0f * bb - prob - 2.0f * giou;
            }
        }
#pragma unroll
        for (int r = 0; r < 4; ++r)
            *(float4*)&C[(size_t)(bq0 + r) * T + t0] =
                make_float4(out[r][0], out[r][1], out[r][2], out[r][3]);
    }
}

// ---------------------------------------------------------------------------
// Kernel 2: per-batch Hungarian (JV / e-maxx), cost[i=target 0..63][j=query 0..299]
// One block (1 wave of 64 threads) per batch. u/v/minv in double to match
// numpy float64 arithmetic bit-exactly (elementwise ops, order-independent min,
// first-index argmin tie-break).
// ---------------------------------------------------------------------------
__global__ __launch_bounds__(64) void hungarian_kernel(
    const float* __restrict__ C,       // [BS,Q,T]
    float* __restrict__ pred_out,      // [BS,TPER]
    float* __restrict__ tgt_out)       // [BS,TPER]
{
    __shared__ float  cost[NROW * M];  // 75 KB: cost[i*M + j]
    __shared__ double v[M + 1], minv[M + 1], u[NROW + 1];
    __shared__ int    p[M + 1], way[M + 1];
    __shared__ unsigned char used[M + 1];

    const int b = blockIdx.x;
    const int tid = threadIdx.x;
    const double INF = 1e18;

    // stage transposed sub-matrix: cost[i][j] = C[b, q=j, b*64+i]
    for (int e = tid; e < NROW * M; e += 64) {
        const int q = e >> 6, i = e & 63;
        cost[i * M + q] = C[(size_t)b * Q * T + (size_t)q * T + b * TPER + i];
    }
    for (int j = tid; j <= M; j += 64) { v[j] = 0.0; p[j] = 0; }
    for (int j = tid; j <= NROW; j += 64) u[j] = 0.0;
    __syncthreads();

    for (int i = 1; i <= NROW; ++i) {
        if (tid == 0) p[0] = i;
        for (int j = tid; j <= M; j += 64) { minv[j] = INF; used[j] = 0; }
        __syncthreads();

        int j0 = 0;
        while (true) {
            if (tid == 0) used[j0] = 1;
            __syncthreads();
            const int    i0  = p[j0];
            const double ui0 = u[i0];
            const float* crow = &cost[(i0 - 1) * M];

            double lmin = INF; int lidx = M + 1;
            for (int j = tid + 1; j <= M; j += 64) {
                if (!used[j]) {
                    double mv = minv[j];
                    double cj = (double)crow[j - 1] - ui0 - v[j];
                    if (cj < mv) { mv = cj; minv[j] = cj; way[j] = j0; }
                    if (mv < lmin) { lmin = mv; lidx = j; }  // strict <: keeps lowest j
                }
            }
            // wave64 (min, idx) reduce; tie -> lower index (numpy argmin semantics)
#pragma unroll
            for (int off = 32; off > 0; off >>= 1) {
                double oval = __shfl_down(lmin, off);
                int    oidx = __shfl_down(lidx, off);
                if (oval < lmin || (oval == lmin && oidx < lidx)) { lmin = oval; lidx = oidx; }
            }
            const int    j1    = __shfl(lidx, 0);
            const double delta = __shfl(lmin, 0);
            __syncthreads();   // scan writes (minv/way) complete before updates

            for (int j = tid; j <= M; j += 64) {
                if (used[j]) { u[p[j]] += delta; v[j] -= delta; }  // p[j] distinct per used j
                else          minv[j] -= delta;
            }
            __syncthreads();
            j0 = j1;
            if (p[j0] == 0) break;
        }
        // augment along alternating path (serial, tiny)
        if (tid == 0) {
            int jj = j0;
            while (jj) { const int j1 = way[jj]; p[jj] = p[j1]; jj = j1; }
        }
        __syncthreads();
    }

    // emit matches in column order: pred = query col, tgt = matched target row
    if (tid == 0) {
        int k = 0;
        for (int j = 1; j <= M; ++j) {
            if (p[j] > 0) {
                pred_out[b * TPER + k] = (float)(j - 1);
                tgt_out [b * TPER + k] = (float)(p[j] - 1);
                ++k;
            }
        }
    }
}

extern "C" void kernel_launch(void* const* d_in, const int* in_sizes, int n_in,
                              void* d_out, int out_size, void* d_ws, size_t ws_size,
                              hipStream_t stream) {
    const float* probs   = (const float*)d_in[0];   // [64,300,91]
    const float* pboxes  = (const float*)d_in[1];   // [64,300,4]
    const float* tboxes  = (const float*)d_in[2];   // [4096,4]
    const int*   tlabels = (const int*)  d_in[3];   // [4096]

    float* C    = (float*)d_out;                    // [64,300,4096]
    float* pred = C + (size_t)BS * Q * T;           // [64,64] as float
    float* tgt  = pred + (size_t)BS * TPER;         // [64,64] as float

    hipLaunchKernelGGL(cost_kernel, dim3(BS * Q / 4), dim3(256), 0, stream,
                       probs, pboxes, tboxes, tlabels, C);
    hipLaunchKernelGGL(hungarian_kernel, dim3(BS), dim3(64), 0, stream,
                       C, pred, tgt);
}

// Round 2
// 445.589 us; speedup vs baseline: 1.3634x; 1.3634x over previous
//
#include <hip/hip_runtime.h>

#define BS   64
#define Q    300
#define K    91
#define T    4096
#define TPER 64
#define M    300   // Hungarian cols (queries)
#define NR   64    // Hungarian rows (targets per batch)
#define WS_STRIDE 304

// ---------------------------------------------------------------------------
// shared cost formula (fast rcp: ~1ulp on O(1) terms, well within tolerance)
// ---------------------------------------------------------------------------
__device__ __forceinline__ float cost_entry(const float4 pb, const float4 tb,
                                            const float prob)
{
    const float px0 = pb.x - pb.z * 0.5f, py0 = pb.y - pb.w * 0.5f;
    const float px1 = pb.x + pb.z * 0.5f, py1 = pb.y + pb.w * 0.5f;
    const float parea = (px1 - px0) * (py1 - py0);
    const float tx0 = tb.x - tb.z * 0.5f, ty0 = tb.y - tb.w * 0.5f;
    const float tx1 = tb.x + tb.z * 0.5f, ty1 = tb.y + tb.w * 0.5f;
    const float tarea = (tx1 - tx0) * (ty1 - ty0);
    const float bb = fabsf(pb.x - tb.x) + fabsf(pb.y - tb.y)
                   + fabsf(pb.z - tb.z) + fabsf(pb.w - tb.w);
    const float iw = fmaxf(fminf(px1, tx1) - fmaxf(px0, tx0), 0.f);
    const float ih = fmaxf(fminf(py1, ty1) - fmaxf(py0, ty0), 0.f);
    const float inter = iw * ih;
    const float uni   = parea + tarea - inter;
    const float iou   = inter * __builtin_amdgcn_rcpf(uni);
    const float cw  = fmaxf(fmaxf(px1, tx1) - fminf(px0, tx0), 0.f);
    const float ch  = fmaxf(fmaxf(py1, ty1) - fminf(py0, ty0), 0.f);
    const float carea = cw * ch;
    const float giou  = iou - (carea - uni) * __builtin_amdgcn_rcpf(carea);
    return 5.0f * bb - prob - 2.0f * giou;
}

// ---------------------------------------------------------------------------
// cost path: one 64-thread block computes 4 (b,q) rows x 4096 targets of C
// ---------------------------------------------------------------------------
__device__ void cost_block(int cb, const float* __restrict__ probs,
                           const float* __restrict__ pboxes,
                           const float* __restrict__ tboxes,
                           const int* __restrict__ tlabels,
                           float* __restrict__ C)
{
    __shared__ float sprobs[4][K];
    const int tid = threadIdx.x;
    const int bq0 = cb * 4;
    for (int idx = tid; idx < 4 * K; idx += 64)
        sprobs[idx / K][idx % K] = probs[(size_t)bq0 * K + idx];
    float4 pbr[4];
#pragma unroll
    for (int r = 0; r < 4; ++r) pbr[r] = ((const float4*)pboxes)[bq0 + r];
    __syncthreads();

#pragma unroll 1
    for (int c = 0; c < 16; ++c) {
        const int t0 = (c << 8) + (tid << 2);
        const int4 lb4 = *(const int4*)(tlabels + t0);
        float out[4][4];
#pragma unroll
        for (int k = 0; k < 4; ++k) {
            const float4 tb = ((const float4*)tboxes)[t0 + k];
            const int lab = (k == 0) ? lb4.x : (k == 1) ? lb4.y : (k == 2) ? lb4.z : lb4.w;
#pragma unroll
            for (int r = 0; r < 4; ++r)
                out[r][k] = cost_entry(pbr[r], tb, sprobs[r][lab]);
        }
#pragma unroll
        for (int r = 0; r < 4; ++r)
            *(float4*)&C[(size_t)(bq0 + r) * T + t0] =
                make_float4(out[r][0], out[r][1], out[r][2], out[r][3]);
    }
}

// ---------------------------------------------------------------------------
// hungarian path: one wave per batch; register-resident JV (e-maxx order-exact)
// lane l owns cols c = 5l..5l+4 (lanes 0..59); lane l holds u[l+1]
// cost slice recomputed into private global ws (row-major [NR][WS_STRIDE])
// ---------------------------------------------------------------------------
__device__ void hungarian_block(int b, const float* __restrict__ probs,
                                const float* __restrict__ pboxes,
                                const float* __restrict__ tboxes,
                                const int* __restrict__ tlabels,
                                float* __restrict__ wslice,
                                float* __restrict__ pred_out,
                                float* __restrict__ tgt_out)
{
    __shared__ int p[M + 1];
    __shared__ int way[M + 1];
    const int tid = threadIdx.x;
    const bool lv = (tid < 60);
    const int c0 = lv ? 5 * tid : 0;

    // ---- recompute this batch's 64x300 slice: cost[i=target][j=query]
    float4 pbx[5];
#pragma unroll
    for (int s = 0; s < 5; ++s)
        pbx[s] = ((const float4*)pboxes)[b * Q + c0 + s];
#pragma unroll 1
    for (int i = 0; i < NR; ++i) {
        const float4 tb = ((const float4*)tboxes)[b * TPER + i];
        const int lab = tlabels[b * TPER + i];
        const size_t pbase = (size_t)(b * Q + c0) * K + lab;
#pragma unroll
        for (int s = 0; s < 5; ++s) {
            const float pr = probs[pbase + (size_t)s * K];
            const float val = cost_entry(pbx[s], tb, pr);
            if (lv) wslice[i * WS_STRIDE + c0 + s] = val;
        }
    }

    // ---- JV state
    double u_reg = 0.0;
    double v_[5], minv_[5];
#pragma unroll
    for (int s = 0; s < 5; ++s) v_[s] = 0.0;
    const unsigned used0 = lv ? 0u : 0x1fu;
    for (int j = tid; j <= M; j += 64) p[j] = 0;
    __syncthreads();

#pragma unroll 1
    for (int i = 1; i <= NR; ++i) {
        if (tid == 0) p[0] = i;
        unsigned usedmask = used0;
        bool inTree = false;
#pragma unroll
        for (int s = 0; s < 5; ++s) minv_[s] = 1e18;
        int i0 = i, j0 = 0;
        float crow[5];
        {
            const float* rp = wslice + (size_t)(i0 - 1) * WS_STRIDE + c0;
#pragma unroll
            for (int s = 0; s < 5; ++s) crow[s] = rp[s];
        }
        int guard = 0;
        while (true) {
            if (tid == i0 - 1) inTree = true;
            const double ui0 = __shfl(u_reg, i0 - 1);
            // scan my 5 cols
            double lmin = 1e18; int lidx = 0x7fffffff;
#pragma unroll
            for (int s = 0; s < 5; ++s) {
                if (!((usedmask >> s) & 1u)) {
                    const double cj = (double)crow[s] - ui0 - v_[s];
                    if (cj < minv_[s]) { minv_[s] = cj; way[c0 + s + 1] = j0; }
                    if (minv_[s] < lmin) { lmin = minv_[s]; lidx = c0 + s; }
                }
            }
            // wave64 (min,val) reduce, tie -> lowest col (numpy argmin)
            double rv = lmin; int ri = lidx;
#pragma unroll
            for (int off = 32; off > 0; off >>= 1) {
                const double ov = __shfl_xor(rv, off);
                const int    oi = __shfl_xor(ri, off);
                if (ov < rv || (ov == rv && oi < ri)) { rv = ov; ri = oi; }
            }
            const double delta = rv;
            const int c1 = ri, j1 = c1 + 1;
            const int i0n = p[j1];                 // LDS broadcast read
            // prefetch next row while we update potentials
            float crow2[5];
            if (i0n) {
                const float* rp2 = wslice + (size_t)(i0n - 1) * WS_STRIDE + c0;
#pragma unroll
                for (int s = 0; s < 5; ++s) crow2[s] = rp2[s];
            }
            if (inTree) u_reg += delta;            // u[p[j]] += delta for used j
#pragma unroll
            for (int s = 0; s < 5; ++s) {
                if ((usedmask >> s) & 1u) v_[s] -= delta;
                else                      minv_[s] -= delta;
            }
            if (lv && c1 >= c0 && c1 < c0 + 5) usedmask |= 1u << (c1 - c0);
            j0 = j1;
            if (!i0n || ++guard > 128) break;
            i0 = i0n;
#pragma unroll
            for (int s = 0; s < 5; ++s) crow[s] = crow2[s];
        }
        __syncthreads();
        if (tid == 0) {                            // augment
            int jj = j0;
            while (jj) { const int jn = way[jj]; p[jj] = p[jn]; jj = jn; }
        }
        __syncthreads();
    }

    // ---- emit matches in column order
    int cnt = 0;
#pragma unroll
    for (int s = 0; s < 5; ++s)
        if (lv && p[c0 + s + 1] > 0) ++cnt;
    int incl = cnt;
#pragma unroll
    for (int off = 1; off < 64; off <<= 1) {
        const int t = __shfl_up(incl, off);
        if (tid >= off) incl += t;
    }
    int pos = incl - cnt;
#pragma unroll
    for (int s = 0; s < 5; ++s) {
        if (lv) {
            const int pi = p[c0 + s + 1];
            if (pi > 0) {
                pred_out[b * TPER + pos] = (float)(c0 + s);
                tgt_out [b * TPER + pos] = (float)(pi - 1);
                ++pos;
            }
        }
    }
}

// ---------------------------------------------------------------------------
// fused kernel: blocks 0..63 hungarian (start first, run long), rest cost
// ---------------------------------------------------------------------------
__global__ __launch_bounds__(64) void fused_kernel(
    const float* __restrict__ probs, const float* __restrict__ pboxes,
    const float* __restrict__ tboxes, const int* __restrict__ tlabels,
    float* __restrict__ C, float* __restrict__ pred_out,
    float* __restrict__ tgt_out, float* __restrict__ ws)
{
    const int bid = blockIdx.x;
    if (bid < BS)
        hungarian_block(bid, probs, pboxes, tboxes, tlabels,
                        ws + (size_t)bid * NR * WS_STRIDE, pred_out, tgt_out);
    else
        cost_block(bid - BS, probs, pboxes, tboxes, tlabels, C);
}

// ===========================================================================
// fallback (round-1 proven path) if ws_size is too small
// ===========================================================================
__global__ __launch_bounds__(256) void cost_kernel_fb(
    const float* __restrict__ probs, const float* __restrict__ pboxes,
    const float* __restrict__ tboxes, const int* __restrict__ tlabels,
    float* __restrict__ C)
{
    __shared__ float sprobs[4][K];
    const int tid = threadIdx.x;
    const int bq0 = blockIdx.x * 4;
    for (int idx = tid; idx < 4 * K; idx += 256)
        sprobs[idx / K][idx % K] = probs[(size_t)bq0 * K + idx];
    float4 pbr[4];
#pragma unroll
    for (int r = 0; r < 4; ++r) pbr[r] = ((const float4*)pboxes)[bq0 + r];
    __syncthreads();
#pragma unroll
    for (int c = 0; c < 4; ++c) {
        const int t0 = (c << 10) + (tid << 2);
        const int4 lb4 = *(const int4*)(tlabels + t0);
        float out[4][4];
#pragma unroll
        for (int k = 0; k < 4; ++k) {
            const float4 tb = ((const float4*)tboxes)[t0 + k];
            const int lab = (k == 0) ? lb4.x : (k == 1) ? lb4.y : (k == 2) ? lb4.z : lb4.w;
#pragma unroll
            for (int r = 0; r < 4; ++r)
                out[r][k] = cost_entry(pbr[r], tb, sprobs[r][lab]);
        }
#pragma unroll
        for (int r = 0; r < 4; ++r)
            *(float4*)&C[(size_t)(bq0 + r) * T + t0] =
                make_float4(out[r][0], out[r][1], out[r][2], out[r][3]);
    }
}

__global__ __launch_bounds__(64) void hungarian_kernel_fb(
    const float* __restrict__ C, float* __restrict__ pred_out,
    float* __restrict__ tgt_out)
{
    __shared__ float  cost[NR * M];
    __shared__ double v[M + 1], minv[M + 1], u[NR + 1];
    __shared__ int    p[M + 1], way[M + 1];
    __shared__ unsigned char used[M + 1];
    const int b = blockIdx.x;
    const int tid = threadIdx.x;
    const double INF = 1e18;
    for (int e = tid; e < NR * M; e += 64) {
        const int q = e >> 6, i = e & 63;
        cost[i * M + q] = C[(size_t)b * Q * T + (size_t)q * T + b * TPER + i];
    }
    for (int j = tid; j <= M; j += 64) { v[j] = 0.0; p[j] = 0; }
    for (int j = tid; j <= NR; j += 64) u[j] = 0.0;
    __syncthreads();
    for (int i = 1; i <= NR; ++i) {
        if (tid == 0) p[0] = i;
        for (int j = tid; j <= M; j += 64) { minv[j] = INF; used[j] = 0; }
        __syncthreads();
        int j0 = 0;
        while (true) {
            if (tid == 0) used[j0] = 1;
            __syncthreads();
            const int    i0  = p[j0];
            const double ui0 = u[i0];
            const float* crow = &cost[(i0 - 1) * M];
            double lmin = INF; int lidx = M + 1;
            for (int j = tid + 1; j <= M; j += 64) {
                if (!used[j]) {
                    double mv = minv[j];
                    const double cj = (double)crow[j - 1] - ui0 - v[j];
                    if (cj < mv) { mv = cj; minv[j] = cj; way[j] = j0; }
                    if (mv < lmin) { lmin = mv; lidx = j; }
                }
            }
#pragma unroll
            for (int off = 32; off > 0; off >>= 1) {
                const double oval = __shfl_down(lmin, off);
                const int    oidx = __shfl_down(lidx, off);
                if (oval < lmin || (oval == lmin && oidx < lidx)) { lmin = oval; lidx = oidx; }
            }
            const int    j1    = __shfl(lidx, 0);
            const double delta = __shfl(lmin, 0);
            __syncthreads();
            for (int j = tid; j <= M; j += 64) {
                if (used[j]) { u[p[j]] += delta; v[j] -= delta; }
                else          minv[j] -= delta;
            }
            __syncthreads();
            j0 = j1;
            if (p[j0] == 0) break;
        }
        if (tid == 0) {
            int jj = j0;
            while (jj) { const int j1 = way[jj]; p[jj] = p[j1]; jj = j1; }
        }
        __syncthreads();
    }
    if (tid == 0) {
        int kk = 0;
        for (int j = 1; j <= M; ++j) {
            if (p[j] > 0) {
                pred_out[b * TPER + kk] = (float)(j - 1);
                tgt_out [b * TPER + kk] = (float)(p[j] - 1);
                ++kk;
            }
        }
    }
}

extern "C" void kernel_launch(void* const* d_in, const int* in_sizes, int n_in,
                              void* d_out, int out_size, void* d_ws, size_t ws_size,
                              hipStream_t stream) {
    const float* probs   = (const float*)d_in[0];   // [64,300,91]
    const float* pboxes  = (const float*)d_in[1];   // [64,300,4]
    const float* tboxes  = (const float*)d_in[2];   // [4096,4]
    const int*   tlabels = (const int*)  d_in[3];   // [4096]

    float* C    = (float*)d_out;                    // [64,300,4096]
    float* pred = C + (size_t)BS * Q * T;           // [64,64] as float
    float* tgt  = pred + (size_t)BS * TPER;         // [64,64] as float

    const size_t ws_needed = (size_t)BS * NR * WS_STRIDE * sizeof(float);
    if (ws_size >= ws_needed) {
        hipLaunchKernelGGL(fused_kernel, dim3(BS + BS * Q / 4), dim3(64), 0, stream,
                           probs, pboxes, tboxes, tlabels, C, pred, tgt, (float*)d_ws);
    } else {
        hipLaunchKernelGGL(cost_kernel_fb, dim3(BS * Q / 4), dim3(256), 0, stream,
                           probs, pboxes, tboxes, tlabels, C);
        hipLaunchKernelGGL(hungarian_kernel_fb, dim3(BS), dim3(64), 0, stream,
                           C, pred, tgt);
    }
}

// Round 3
// 407.596 us; speedup vs baseline: 1.4904x; 1.0932x over previous
//
#include <hip/hip_runtime.h>

#define BS   64
#define Q    300
#define K    91
#define T    4096
#define TPER 64
#define M    300   // Hungarian cols (queries)
#define NR   64    // Hungarian rows (targets per batch)
#define WS_STRIDE 304

// ---------------------------------------------------------------------------
// shared cost formula (fast rcp: ~1ulp on O(1) terms, well within tolerance)
// ---------------------------------------------------------------------------
__device__ __forceinline__ float cost_entry(const float4 pb, const float4 tb,
                                            const float prob)
{
    const float px0 = pb.x - pb.z * 0.5f, py0 = pb.y - pb.w * 0.5f;
    const float px1 = pb.x + pb.z * 0.5f, py1 = pb.y + pb.w * 0.5f;
    const float parea = (px1 - px0) * (py1 - py0);
    const float tx0 = tb.x - tb.z * 0.5f, ty0 = tb.y - tb.w * 0.5f;
    const float tx1 = tb.x + tb.z * 0.5f, ty1 = tb.y + tb.w * 0.5f;
    const float tarea = (tx1 - tx0) * (ty1 - ty0);
    const float bb = fabsf(pb.x - tb.x) + fabsf(pb.y - tb.y)
                   + fabsf(pb.z - tb.z) + fabsf(pb.w - tb.w);
    const float iw = fmaxf(fminf(px1, tx1) - fmaxf(px0, tx0), 0.f);
    const float ih = fmaxf(fminf(py1, ty1) - fmaxf(py0, ty0), 0.f);
    const float inter = iw * ih;
    const float uni   = parea + tarea - inter;
    const float iou   = inter * __builtin_amdgcn_rcpf(uni);
    const float cw  = fmaxf(fmaxf(px1, tx1) - fminf(px0, tx0), 0.f);
    const float ch  = fmaxf(fmaxf(py1, ty1) - fminf(py0, ty0), 0.f);
    const float carea = cw * ch;
    const float giou  = iou - (carea - uni) * __builtin_amdgcn_rcpf(carea);
    return 5.0f * bb - prob - 2.0f * giou;
}

// ---------------------------------------------------------------------------
// cost path: one 64-thread block computes 4 (b,q) rows x 4096 targets of C
// ---------------------------------------------------------------------------
__device__ void cost_block(int cb, const float* __restrict__ probs,
                           const float* __restrict__ pboxes,
                           const float* __restrict__ tboxes,
                           const int* __restrict__ tlabels,
                           float* __restrict__ C)
{
    __shared__ float sprobs[4][K];
    const int tid = threadIdx.x;
    const int bq0 = cb * 4;
    for (int idx = tid; idx < 4 * K; idx += 64)
        sprobs[idx / K][idx % K] = probs[(size_t)bq0 * K + idx];
    float4 pbr[4];
#pragma unroll
    for (int r = 0; r < 4; ++r) pbr[r] = ((const float4*)pboxes)[bq0 + r];
    __syncthreads();

#pragma unroll 1
    for (int c = 0; c < 16; ++c) {
        const int t0 = (c << 8) + (tid << 2);
        const int4 lb4 = *(const int4*)(tlabels + t0);
        float out[4][4];
#pragma unroll
        for (int k = 0; k < 4; ++k) {
            const float4 tb = ((const float4*)tboxes)[t0 + k];
            const int lab = (k == 0) ? lb4.x : (k == 1) ? lb4.y : (k == 2) ? lb4.z : lb4.w;
#pragma unroll
            for (int r = 0; r < 4; ++r)
                out[r][k] = cost_entry(pbr[r], tb, sprobs[r][lab]);
        }
#pragma unroll
        for (int r = 0; r < 4; ++r)
            *(float4*)&C[(size_t)(bq0 + r) * T + t0] =
                make_float4(out[r][0], out[r][1], out[r][2], out[r][3]);
    }
}

// ---------------------------------------------------------------------------
// hungarian path: one wave per batch; register-resident JV (e-maxx core,
// proven round 2) + greedy dual-feasible init (u[i]=rowmin, claim argmin col).
// Any dual-feasible init yields the same unique-optimum assignment.
// lane l owns cols c = 5l..5l+4 (lanes 0..59); lane l holds u[l+1]
// ---------------------------------------------------------------------------
__device__ void hungarian_block(int b, const float* __restrict__ probs,
                                const float* __restrict__ pboxes,
                                const float* __restrict__ tboxes,
                                const int* __restrict__ tlabels,
                                float* __restrict__ wslice,
                                float* __restrict__ pred_out,
                                float* __restrict__ tgt_out)
{
    __shared__ int p[M + 1];
    __shared__ int way[M + 1];
    const int tid = threadIdx.x;
    const bool lv = (tid < 60);
    const int c0 = lv ? 5 * tid : 0;

    // ---- recompute this batch's 64x300 slice: cost[i=target][j=query]
    float4 pbx[5];
#pragma unroll
    for (int s = 0; s < 5; ++s)
        pbx[s] = ((const float4*)pboxes)[b * Q + c0 + s];
#pragma unroll 1
    for (int i = 0; i < NR; ++i) {
        const float4 tb = ((const float4*)tboxes)[b * TPER + i];
        const int lab = tlabels[b * TPER + i];
        const size_t pbase = (size_t)(b * Q + c0) * K + lab;
#pragma unroll
        for (int s = 0; s < 5; ++s) {
            const float pr = probs[pbase + (size_t)s * K];
            const float val = cost_entry(pbx[s], tb, pr);
            if (lv) wslice[i * WS_STRIDE + c0 + s] = val;
        }
    }
    for (int j = tid; j <= M; j += 64) p[j] = 0;
    __threadfence_block();   // writes visible to all lanes (same CU, L1 write-through)
    __syncthreads();

    // ---- greedy init: lane i scans row i for (min, argmin); strict < = lowest idx
    float rmin = 1e30f; int rarg = 0;
    const float4* rowp = (const float4*)(wslice + tid * WS_STRIDE);
#pragma unroll 1
    for (int c4 = 0; c4 < 75; ++c4) {
        const float4 vq = rowp[c4];
        if (vq.x < rmin) { rmin = vq.x; rarg = c4 * 4 + 0; }
        if (vq.y < rmin) { rmin = vq.y; rarg = c4 * 4 + 1; }
        if (vq.z < rmin) { rmin = vq.z; rarg = c4 * 4 + 2; }
        if (vq.w < rmin) { rmin = vq.w; rarg = c4 * 4 + 3; }
    }
    double u_reg = (double)rmin;          // u[tid+1] = rowmin (dual-feasible, v=0)

    // claim argmin cols in row order (uniform control flow; tid0 writes p)
    unsigned long long matchedRows = 0ull;
#pragma unroll 1
    for (int r = 0; r < NR; ++r) {
        const int ac = __shfl(rarg, r);
        const int pj = p[ac + 1];
        if (pj == 0) {                     // free col: tight edge, claim it
            if (tid == 0) p[ac + 1] = r + 1;
            matchedRows |= 1ull << r;
        }
        __syncthreads();                   // order tid0's LDS write vs next read
    }

    // ---- JV state
    double v_[5], minv_[5];
#pragma unroll
    for (int s = 0; s < 5; ++s) v_[s] = 0.0;
    const unsigned used0 = lv ? 0u : 0x1fu;

#pragma unroll 1
    for (int i = 1; i <= NR; ++i) {
        if ((matchedRows >> (i - 1)) & 1ull) continue;   // greedily matched
        if (tid == 0) p[0] = i;
        unsigned usedmask = used0;
        bool inTree = false;
#pragma unroll
        for (int s = 0; s < 5; ++s) minv_[s] = 1e18;
        int i0 = i, j0 = 0;
        float crow[5];
        {
            const float* rp = wslice + (size_t)(i0 - 1) * WS_STRIDE + c0;
#pragma unroll
            for (int s = 0; s < 5; ++s) crow[s] = rp[s];
        }
        int guard = 0;
        while (true) {
            if (tid == i0 - 1) inTree = true;
            const double ui0 = __shfl(u_reg, i0 - 1);
            // scan my 5 cols
            double lmin = 1e18; int lidx = 0x7fffffff;
#pragma unroll
            for (int s = 0; s < 5; ++s) {
                if (!((usedmask >> s) & 1u)) {
                    const double cj = (double)crow[s] - ui0 - v_[s];
                    if (cj < minv_[s]) { minv_[s] = cj; way[c0 + s + 1] = j0; }
                    if (minv_[s] < lmin) { lmin = minv_[s]; lidx = c0 + s; }
                }
            }
            // wave64 (min,val) reduce, tie -> lowest col (numpy argmin)
            double rv = lmin; int ri = lidx;
#pragma unroll
            for (int off = 32; off > 0; off >>= 1) {
                const double ov = __shfl_xor(rv, off);
                const int    oi = __shfl_xor(ri, off);
                if (ov < rv || (ov == rv && oi < ri)) { rv = ov; ri = oi; }
            }
            const double delta = rv;
            const int c1 = ri, j1 = c1 + 1;
            const int i0n = p[j1];                 // LDS broadcast read
            // prefetch next row while we update potentials
            float crow2[5];
            if (i0n) {
                const float* rp2 = wslice + (size_t)(i0n - 1) * WS_STRIDE + c0;
#pragma unroll
                for (int s = 0; s < 5; ++s) crow2[s] = rp2[s];
            }
            if (inTree) u_reg += delta;            // u[p[j]] += delta for used j
#pragma unroll
            for (int s = 0; s < 5; ++s) {
                if ((usedmask >> s) & 1u) v_[s] -= delta;
                else                      minv_[s] -= delta;
            }
            if (lv && c1 >= c0 && c1 < c0 + 5) usedmask |= 1u << (c1 - c0);
            j0 = j1;
            if (!i0n || ++guard > 512) break;
            i0 = i0n;
#pragma unroll
            for (int s = 0; s < 5; ++s) crow[s] = crow2[s];
        }
        __syncthreads();
        if (tid == 0) {                            // augment
            int jj = j0;
            while (jj) { const int jn = way[jj]; p[jj] = p[jn]; jj = jn; }
        }
        __syncthreads();
    }

    // ---- emit matches in column order
    int cnt = 0;
#pragma unroll
    for (int s = 0; s < 5; ++s)
        if (lv && p[c0 + s + 1] > 0) ++cnt;
    int incl = cnt;
#pragma unroll
    for (int off = 1; off < 64; off <<= 1) {
        const int t = __shfl_up(incl, off);
        if (tid >= off) incl += t;
    }
    int pos = incl - cnt;
#pragma unroll
    for (int s = 0; s < 5; ++s) {
        if (lv) {
            const int pi = p[c0 + s + 1];
            if (pi > 0) {
                pred_out[b * TPER + pos] = (float)(c0 + s);
                tgt_out [b * TPER + pos] = (float)(pi - 1);
                ++pos;
            }
        }
    }
}

// ---------------------------------------------------------------------------
// fused kernel: blocks 0..63 hungarian (start first, run long), rest cost
// ---------------------------------------------------------------------------
__global__ __launch_bounds__(64) void fused_kernel(
    const float* __restrict__ probs, const float* __restrict__ pboxes,
    const float* __restrict__ tboxes, const int* __restrict__ tlabels,
    float* __restrict__ C, float* __restrict__ pred_out,
    float* __restrict__ tgt_out, float* __restrict__ ws)
{
    const int bid = blockIdx.x;
    if (bid < BS)
        hungarian_block(bid, probs, pboxes, tboxes, tlabels,
                        ws + (size_t)bid * NR * WS_STRIDE, pred_out, tgt_out);
    else
        cost_block(bid - BS, probs, pboxes, tboxes, tlabels, C);
}

// ===========================================================================
// fallback (round-1 proven path) if ws_size is too small
// ===========================================================================
__global__ __launch_bounds__(256) void cost_kernel_fb(
    const float* __restrict__ probs, const float* __restrict__ pboxes,
    const float* __restrict__ tboxes, const int* __restrict__ tlabels,
    float* __restrict__ C)
{
    __shared__ float sprobs[4][K];
    const int tid = threadIdx.x;
    const int bq0 = blockIdx.x * 4;
    for (int idx = tid; idx < 4 * K; idx += 256)
        sprobs[idx / K][idx % K] = probs[(size_t)bq0 * K + idx];
    float4 pbr[4];
#pragma unroll
    for (int r = 0; r < 4; ++r) pbr[r] = ((const float4*)pboxes)[bq0 + r];
    __syncthreads();
#pragma unroll
    for (int c = 0; c < 4; ++c) {
        const int t0 = (c << 10) + (tid << 2);
        const int4 lb4 = *(const int4*)(tlabels + t0);
        float out[4][4];
#pragma unroll
        for (int k = 0; k < 4; ++k) {
            const float4 tb = ((const float4*)tboxes)[t0 + k];
            const int lab = (k == 0) ? lb4.x : (k == 1) ? lb4.y : (k == 2) ? lb4.z : lb4.w;
#pragma unroll
            for (int r = 0; r < 4; ++r)
                out[r][k] = cost_entry(pbr[r], tb, sprobs[r][lab]);
        }
#pragma unroll
        for (int r = 0; r < 4; ++r)
            *(float4*)&C[(size_t)(bq0 + r) * T + t0] =
                make_float4(out[r][0], out[r][1], out[r][2], out[r][3]);
    }
}

__global__ __launch_bounds__(64) void hungarian_kernel_fb(
    const float* __restrict__ C, float* __restrict__ pred_out,
    float* __restrict__ tgt_out)
{
    __shared__ float  cost[NR * M];
    __shared__ double v[M + 1], minv[M + 1], u[NR + 1];
    __shared__ int    p[M + 1], way[M + 1];
    __shared__ unsigned char used[M + 1];
    const int b = blockIdx.x;
    const int tid = threadIdx.x;
    const double INF = 1e18;
    for (int e = tid; e < NR * M; e += 64) {
        const int q = e >> 6, i = e & 63;
        cost[i * M + q] = C[(size_t)b * Q * T + (size_t)q * T + b * TPER + i];
    }
    for (int j = tid; j <= M; j += 64) { v[j] = 0.0; p[j] = 0; }
    for (int j = tid; j <= NR; j += 64) u[j] = 0.0;
    __syncthreads();
    for (int i = 1; i <= NR; ++i) {
        if (tid == 0) p[0] = i;
        for (int j = tid; j <= M; j += 64) { minv[j] = INF; used[j] = 0; }
        __syncthreads();
        int j0 = 0;
        while (true) {
            if (tid == 0) used[j0] = 1;
            __syncthreads();
            const int    i0  = p[j0];
            const double ui0 = u[i0];
            const float* crow = &cost[(i0 - 1) * M];
            double lmin = INF; int lidx = M + 1;
            for (int j = tid + 1; j <= M; j += 64) {
                if (!used[j]) {
                    double mv = minv[j];
                    const double cj = (double)crow[j - 1] - ui0 - v[j];
                    if (cj < mv) { mv = cj; minv[j] = cj; way[j] = j0; }
                    if (mv < lmin) { lmin = mv; lidx = j; }
                }
            }
#pragma unroll
            for (int off = 32; off > 0; off >>= 1) {
                const double oval = __shfl_down(lmin, off);
                const int    oidx = __shfl_down(lidx, off);
                if (oval < lmin || (oval == lmin && oidx < lidx)) { lmin = oval; lidx = oidx; }
            }
            const int    j1    = __shfl(lidx, 0);
            const double delta = __shfl(lmin, 0);
            __syncthreads();
            for (int j = tid; j <= M; j += 64) {
                if (used[j]) { u[p[j]] += delta; v[j] -= delta; }
                else          minv[j] -= delta;
            }
            __syncthreads();
            j0 = j1;
            if (p[j0] == 0) break;
        }
        if (tid == 0) {
            int jj = j0;
            while (jj) { const int j1 = way[jj]; p[jj] = p[j1]; jj = j1; }
        }
        __syncthreads();
    }
    if (tid == 0) {
        int kk = 0;
        for (int j = 1; j <= M; ++j) {
            if (p[j] > 0) {
                pred_out[b * TPER + kk] = (float)(j - 1);
                tgt_out [b * TPER + kk] = (float)(p[j] - 1);
                ++kk;
            }
        }
    }
}

extern "C" void kernel_launch(void* const* d_in, const int* in_sizes, int n_in,
                              void* d_out, int out_size, void* d_ws, size_t ws_size,
                              hipStream_t stream) {
    const float* probs   = (const float*)d_in[0];   // [64,300,91]
    const float* pboxes  = (const float*)d_in[1];   // [64,300,4]
    const float* tboxes  = (const float*)d_in[2];   // [4096,4]
    const int*   tlabels = (const int*)  d_in[3];   // [4096]

    float* C    = (float*)d_out;                    // [64,300,4096]
    float* pred = C + (size_t)BS * Q * T;           // [64,64] as float
    float* tgt  = pred + (size_t)BS * TPER;         // [64,64] as float

    const size_t ws_needed = (size_t)BS * NR * WS_STRIDE * sizeof(float);
    if (ws_size >= ws_needed) {
        hipLaunchKernelGGL(fused_kernel, dim3(BS + BS * Q / 4), dim3(64), 0, stream,
                           probs, pboxes, tboxes, tlabels, C, pred, tgt, (float*)d_ws);
    } else {
        hipLaunchKernelGGL(cost_kernel_fb, dim3(BS * Q / 4), dim3(256), 0, stream,
                           probs, pboxes, tboxes, tlabels, C);
        hipLaunchKernelGGL(hungarian_kernel_fb, dim3(BS), dim3(64), 0, stream,
                           C, pred, tgt);
    }
}